// Round 4
// baseline (576.580 us; speedup 1.0000x reference)
//
#include <hip/hip_runtime.h>
#include <math.h>

#define NODES  50000
#define EDGES  800000
#define GRAPHS 256
#define FEAT   128
#define STATE  64
#define M_OUT  32
#define ROUNDS 4
#define NTILES ((NODES + 15) / 16)
#define NB     4          // src buckets
#define BUCKET 12500      // nodes per bucket (12500*256B = 3.2MB message slice, fits 4MB L2)

// ---------------------------------------------------------------------------
// 8-deep MLP gather: sum of msg[csr[beg..end)] float4-slices at offset jg.
// Tail indices clamped to end-1, masked by 0-multiplier (keeps 8 loads in flight).
// ---------------------------------------------------------------------------
__device__ __forceinline__ float4 gather_sum8(const int* __restrict__ csr,
                                              const float* __restrict__ msg,
                                              int beg, int end, int jg)
{
    float4 acc = make_float4(0.f, 0.f, 0.f, 0.f);
    for (int i = beg; i < end; i += 8) {
        int last = end - 1;
        int i1 = i + 1 < last ? i + 1 : last;
        int i2 = i + 2 < last ? i + 2 : last;
        int i3 = i + 3 < last ? i + 3 : last;
        int i4 = i + 4 < last ? i + 4 : last;
        int i5 = i + 5 < last ? i + 5 : last;
        int i6 = i + 6 < last ? i + 6 : last;
        int i7 = i + 7 < last ? i + 7 : last;
        int s0 = csr[i],  s1 = csr[i1], s2 = csr[i2], s3 = csr[i3];
        int s4 = csr[i4], s5 = csr[i5], s6 = csr[i6], s7 = csr[i7];
        float4 v0 = *(const float4*)(msg + (long)s0 * STATE + jg);
        float4 v1 = *(const float4*)(msg + (long)s1 * STATE + jg);
        float4 v2 = *(const float4*)(msg + (long)s2 * STATE + jg);
        float4 v3 = *(const float4*)(msg + (long)s3 * STATE + jg);
        float4 v4 = *(const float4*)(msg + (long)s4 * STATE + jg);
        float4 v5 = *(const float4*)(msg + (long)s5 * STATE + jg);
        float4 v6 = *(const float4*)(msg + (long)s6 * STATE + jg);
        float4 v7 = *(const float4*)(msg + (long)s7 * STATE + jg);
        float m1 = (i + 1 < end) ? 1.f : 0.f;
        float m2 = (i + 2 < end) ? 1.f : 0.f;
        float m3 = (i + 3 < end) ? 1.f : 0.f;
        float m4 = (i + 4 < end) ? 1.f : 0.f;
        float m5 = (i + 5 < end) ? 1.f : 0.f;
        float m6 = (i + 6 < end) ? 1.f : 0.f;
        float m7 = (i + 7 < end) ? 1.f : 0.f;
        acc.x += v0.x; acc.y += v0.y; acc.z += v0.z; acc.w += v0.w;
        acc.x += v1.x * m1; acc.y += v1.y * m1; acc.z += v1.z * m1; acc.w += v1.w * m1;
        acc.x += v2.x * m2; acc.y += v2.y * m2; acc.z += v2.z * m2; acc.w += v2.w * m2;
        acc.x += v3.x * m3; acc.y += v3.y * m3; acc.z += v3.z * m3; acc.w += v3.w * m3;
        acc.x += v4.x * m4; acc.y += v4.y * m4; acc.z += v4.z * m4; acc.w += v4.w * m4;
        acc.x += v5.x * m5; acc.y += v5.y * m5; acc.z += v5.z * m5; acc.w += v5.w * m5;
        acc.x += v6.x * m6; acc.y += v6.y * m6; acc.z += v6.z * m6; acc.w += v6.w * m6;
        acc.x += v7.x * m7; acc.y += v7.y * m7; acc.z += v7.z * m7; acc.w += v7.w * m7;
    }
    return acc;
}

// Bucketed gather: loop src-buckets in chip-uniform order for L2 residency.
__device__ __forceinline__ float4 gather_buckets(const int* __restrict__ bptr,
                                                 const int* __restrict__ csr,
                                                 const float* __restrict__ msg,
                                                 int n, int jg)
{
    float4 acc = make_float4(0.f, 0.f, 0.f, 0.f);
    const int pb = n * NB;
    #pragma unroll 1
    for (int b = 0; b < NB; b++) {
        int beg = bptr[pb + b], end = bptr[pb + b + 1];
        float4 p = gather_sum8(csr, msg, beg, end, jg);
        acc.x += p.x; acc.y += p.y; acc.z += p.z; acc.w += p.w;
    }
    return acc;
}

// ---------------------------------------------------------------------------
// Fused: state = relu(x @ inW + inb); message = relu(state @ msgW + msgb)
// ---------------------------------------------------------------------------
__global__ __launch_bounds__(256) void k_in_msg(
    const float* __restrict__ x, const float* __restrict__ inW, const float* __restrict__ inb,
    const float* __restrict__ msgW, const float* __restrict__ msgb,
    float* __restrict__ state, float* __restrict__ message)
{
    __shared__ float sInW[FEAT * STATE];    // 32 KB
    __shared__ float sMsgW[STATE * STATE];  // 16 KB
    __shared__ float sInb[STATE], sMsgb[STATE];
    __shared__ float sx[16 * 132];
    __shared__ float ss[16 * 68];

    for (int i = threadIdx.x; i < (FEAT * STATE) / 4; i += 256)
        *(float4*)(sInW + i * 4) = *(const float4*)(inW + i * 4);
    for (int i = threadIdx.x; i < (STATE * STATE) / 4; i += 256)
        *(float4*)(sMsgW + i * 4) = *(const float4*)(msgW + i * 4);
    if (threadIdx.x < STATE) {
        sInb[threadIdx.x]  = inb[threadIdx.x];
        sMsgb[threadIdx.x] = msgb[threadIdx.x];
    }

    const int ns = threadIdx.x >> 4;
    const int jg = (threadIdx.x & 15) << 2;

    for (int base = blockIdx.x * 16; base < NODES; base += gridDim.x * 16) {
        __syncthreads();
        for (int i = threadIdx.x; i < 512; i += 256) {
            int row = i >> 5, q = (i & 31) << 2;
            int n = base + row;
            float4 v = make_float4(0.f, 0.f, 0.f, 0.f);
            if (n < NODES) v = *(const float4*)(x + (long)n * FEAT + q);
            *(float4*)(sx + row * 132 + q) = v;
        }
        __syncthreads();

        const int n = base + ns;
        float a0 = sInb[jg], a1 = sInb[jg + 1], a2 = sInb[jg + 2], a3 = sInb[jg + 3];
        const float* xr = sx + ns * 132;
        #pragma unroll 8
        for (int k = 0; k < FEAT; k++) {
            float xv = xr[k];
            float4 w = *(const float4*)(sInW + k * STATE + jg);
            a0 += xv * w.x; a1 += xv * w.y; a2 += xv * w.z; a3 += xv * w.w;
        }
        a0 = fmaxf(a0, 0.f); a1 = fmaxf(a1, 0.f); a2 = fmaxf(a2, 0.f); a3 = fmaxf(a3, 0.f);
        if (n < NODES) *(float4*)(state + (long)n * STATE + jg) = make_float4(a0, a1, a2, a3);
        *(float4*)(ss + ns * 68 + jg) = make_float4(a0, a1, a2, a3);
        __syncthreads();

        float m0 = sMsgb[jg], m1 = sMsgb[jg + 1], m2 = sMsgb[jg + 2], m3 = sMsgb[jg + 3];
        const float* sr = ss + ns * 68;
        #pragma unroll 8
        for (int k = 0; k < STATE; k++) {
            float sv = sr[k];
            float4 w = *(const float4*)(sMsgW + k * STATE + jg);
            m0 += sv * w.x; m1 += sv * w.y; m2 += sv * w.z; m3 += sv * w.w;
        }
        m0 = fmaxf(m0, 0.f); m1 = fmaxf(m1, 0.f); m2 = fmaxf(m2, 0.f); m3 = fmaxf(m3, 0.f);
        if (n < NODES) *(float4*)(message + (long)n * STATE + jg) = make_float4(m0, m1, m2, m3);
    }
}

// ---------------------------------------------------------------------------
// CSR build: per-(dst, src-bucket) histogram
// ---------------------------------------------------------------------------
__global__ __launch_bounds__(256) void k_hist(const int* __restrict__ ei, int* __restrict__ deg2)
{
    int e = blockIdx.x * 256 + threadIdx.x;
    if (e < EDGES) {
        int src = ei[e];
        int dst = ei[EDGES + e];
        atomicAdd(&deg2[dst * NB + src / BUCKET], 1);
    }
}

// Exclusive scan of per-node total degree (sum of 4 bucket counts) -> rowptr
__global__ __launch_bounds__(1024) void k_scan(const int* __restrict__ deg2,
                                               int* __restrict__ rowptr)
{
    __shared__ int wsum[16];
    __shared__ int carry;
    const int tid = threadIdx.x;
    const int lane = tid & 63, wid = tid >> 6;
    if (tid == 0) carry = 0;
    __syncthreads();
    for (int base = 0; base < NODES; base += 1024) {
        int n = base + tid;
        int v = 0;
        if (n < NODES) {
            int4 d = *(const int4*)(deg2 + n * NB);
            v = d.x + d.y + d.z + d.w;
        }
        int incl = v;
        #pragma unroll
        for (int off = 1; off < 64; off <<= 1) {
            int t = __shfl_up(incl, off, 64);
            if (lane >= off) incl += t;
        }
        if (lane == 63) wsum[wid] = incl;
        __syncthreads();
        if (tid < 16) {
            int t = wsum[tid];
            #pragma unroll
            for (int off = 1; off < 16; off <<= 1) {
                int u = __shfl_up(t, off, 64);
                if (tid >= off) t += u;
            }
            wsum[tid] = t;
        }
        __syncthreads();
        int wbase = (wid == 0) ? 0 : wsum[wid - 1];
        int excl = carry + wbase + incl - v;
        if (n < NODES) rowptr[n] = excl;
        int tot = wsum[15];
        __syncthreads();
        if (tid == 0) carry += tot;
        __syncthreads();
    }
    if (tid == 0) rowptr[NODES] = carry;
}

// Per-(node,bucket) segment pointers: bptr[n*NB+b] = rowptr[n] + prefix(deg2[n][0..b))
__global__ __launch_bounds__(256) void k_bptr(const int* __restrict__ deg2,
                                              const int* __restrict__ rowptr,
                                              int* __restrict__ bptr,
                                              int* __restrict__ cursor)
{
    int n = blockIdx.x * 256 + threadIdx.x;
    if (n < NODES) {
        int4 d = *(const int4*)(deg2 + n * NB);
        int r = rowptr[n];
        int p0 = r, p1 = p0 + d.x, p2 = p1 + d.y, p3 = p2 + d.z;
        bptr[n * NB + 0] = p0; bptr[n * NB + 1] = p1;
        bptr[n * NB + 2] = p2; bptr[n * NB + 3] = p3;
        cursor[n * NB + 0] = p0; cursor[n * NB + 1] = p1;
        cursor[n * NB + 2] = p2; cursor[n * NB + 3] = p3;
    }
    if (n == 0) bptr[NODES * NB] = EDGES;
}

__global__ __launch_bounds__(256) void k_fill(const int* __restrict__ ei,
                                              int* __restrict__ cursor,
                                              int* __restrict__ csr)
{
    int e = blockIdx.x * 256 + threadIdx.x;
    if (e < EDGES) {
        int src = ei[e];
        int dst = ei[EDGES + e];
        int slot = atomicAdd(&cursor[dst * NB + src / BUCKET], 1);
        csr[slot] = src;
    }
}

// ---------------------------------------------------------------------------
// Pull aggregation (bucketed, 8-deep MLP) fused with update + next message.
// ---------------------------------------------------------------------------
__global__ __launch_bounds__(256) void k_agg_upd_msg(
    const float* __restrict__ updW, const float* __restrict__ updb,
    const float* __restrict__ msgW, const float* __restrict__ msgb,
    const int* __restrict__ bptr, const int* __restrict__ csr,
    const float* __restrict__ msg_in,
    float* __restrict__ state, float* __restrict__ msg_out)
{
    __shared__ float sUpdW[STATE * STATE], sMsgW[STATE * STATE];
    __shared__ float sUpdb[STATE], sMsgb[STATE];
    __shared__ float sa[16 * 68], ss[16 * 68];

    for (int i = threadIdx.x; i < (STATE * STATE) / 4; i += 256) {
        *(float4*)(sUpdW + i * 4) = *(const float4*)(updW + i * 4);
        *(float4*)(sMsgW + i * 4) = *(const float4*)(msgW + i * 4);
    }
    if (threadIdx.x < STATE) {
        sUpdb[threadIdx.x] = updb[threadIdx.x];
        sMsgb[threadIdx.x] = msgb[threadIdx.x];
    }

    const int ns = threadIdx.x >> 4;
    const int jg = (threadIdx.x & 15) << 2;

    for (int base = blockIdx.x * 16; base < NODES; base += gridDim.x * 16) {
        const int n = base + ns;
        float4 acc = make_float4(0.f, 0.f, 0.f, 0.f);
        if (n < NODES) acc = gather_buckets(bptr, csr, msg_in, n, jg);
        __syncthreads();
        *(float4*)(sa + ns * 68 + jg) = acc;
        __syncthreads();

        float a0 = sUpdb[jg], a1 = sUpdb[jg + 1], a2 = sUpdb[jg + 2], a3 = sUpdb[jg + 3];
        const float* ar = sa + ns * 68;
        #pragma unroll 8
        for (int k = 0; k < STATE; k++) {
            float av = ar[k];
            float4 w = *(const float4*)(sUpdW + k * STATE + jg);
            a0 += av * w.x; a1 += av * w.y; a2 += av * w.z; a3 += av * w.w;
        }
        a0 = fmaxf(a0, 0.f); a1 = fmaxf(a1, 0.f); a2 = fmaxf(a2, 0.f); a3 = fmaxf(a3, 0.f);
        float4 st = make_float4(0.f, 0.f, 0.f, 0.f);
        if (n < NODES) st = *(const float4*)(state + (long)n * STATE + jg);
        float s0 = st.x + a0, s1 = st.y + a1, s2 = st.z + a2, s3 = st.w + a3;
        if (n < NODES) *(float4*)(state + (long)n * STATE + jg) = make_float4(s0, s1, s2, s3);
        *(float4*)(ss + ns * 68 + jg) = make_float4(s0, s1, s2, s3);
        __syncthreads();

        float m0 = sMsgb[jg], m1 = sMsgb[jg + 1], m2 = sMsgb[jg + 2], m3 = sMsgb[jg + 3];
        const float* sr = ss + ns * 68;
        #pragma unroll 8
        for (int k = 0; k < STATE; k++) {
            float sv = sr[k];
            float4 w = *(const float4*)(sMsgW + k * STATE + jg);
            m0 += sv * w.x; m1 += sv * w.y; m2 += sv * w.z; m3 += sv * w.w;
        }
        m0 = fmaxf(m0, 0.f); m1 = fmaxf(m1, 0.f); m2 = fmaxf(m2, 0.f); m3 = fmaxf(m3, 0.f);
        if (n < NODES) *(float4*)(msg_out + (long)n * STATE + jg) = make_float4(m0, m1, m2, m3);
    }
}

// ---------------------------------------------------------------------------
// Last round: aggregation + update fused with graph pooling.
// ---------------------------------------------------------------------------
__global__ __launch_bounds__(256) void k_agg_upd_pool(
    const float* __restrict__ updW, const float* __restrict__ updb,
    const int* __restrict__ bptr, const int* __restrict__ csr,
    const float* __restrict__ msg_in,
    const float* __restrict__ state, const int* __restrict__ batch,
    float* __restrict__ gs)
{
    __shared__ float sUpdW[STATE * STATE];
    __shared__ float sUpdb[STATE];
    __shared__ float sa[16 * 68];

    for (int i = threadIdx.x; i < (STATE * STATE) / 4; i += 256)
        *(float4*)(sUpdW + i * 4) = *(const float4*)(updW + i * 4);
    if (threadIdx.x < STATE) sUpdb[threadIdx.x] = updb[threadIdx.x];

    const int ns = threadIdx.x >> 4;
    const int jg = (threadIdx.x & 15) << 2;

    for (int base = blockIdx.x * 16; base < NODES; base += gridDim.x * 16) {
        const int n = base + ns;
        float4 acc = make_float4(0.f, 0.f, 0.f, 0.f);
        if (n < NODES) acc = gather_buckets(bptr, csr, msg_in, n, jg);
        __syncthreads();
        *(float4*)(sa + ns * 68 + jg) = acc;
        __syncthreads();

        float a0 = sUpdb[jg], a1 = sUpdb[jg + 1], a2 = sUpdb[jg + 2], a3 = sUpdb[jg + 3];
        const float* ar = sa + ns * 68;
        #pragma unroll 8
        for (int k = 0; k < STATE; k++) {
            float av = ar[k];
            float4 w = *(const float4*)(sUpdW + k * STATE + jg);
            a0 += av * w.x; a1 += av * w.y; a2 += av * w.z; a3 += av * w.w;
        }
        a0 = fmaxf(a0, 0.f); a1 = fmaxf(a1, 0.f); a2 = fmaxf(a2, 0.f); a3 = fmaxf(a3, 0.f);
        if (n < NODES) {
            float4 st = *(const float4*)(state + (long)n * STATE + jg);
            int g = batch[n];
            float* p = gs + (long)g * STATE + jg;
            atomicAdd(p + 0, st.x + a0);
            atomicAdd(p + 1, st.y + a1);
            atomicAdd(p + 2, st.z + a2);
            atomicAdd(p + 3, st.w + a3);
        }
        __syncthreads();
    }
}

// ---------------------------------------------------------------------------
// mean = gs@meanW+b ; std = exp(0.5*clip(gs@lvW+b, -20, 2)) -> out[2,256,32]
// ---------------------------------------------------------------------------
__global__ __launch_bounds__(64) void k_final(
    const float* __restrict__ gs,
    const float* __restrict__ meanW, const float* __restrict__ meanb,
    const float* __restrict__ lvW, const float* __restrict__ lvb,
    float* __restrict__ out)
{
    __shared__ float row[STATE];
    const int g = blockIdx.x;
    const int j = threadIdx.x;
    row[j] = gs[g * STATE + j];
    __syncthreads();
    if (j < M_OUT) {
        float acc = meanb[j];
        #pragma unroll
        for (int k = 0; k < STATE; k++) acc += row[k] * meanW[k * M_OUT + j];
        out[g * M_OUT + j] = acc;
    } else {
        int jj = j - M_OUT;
        float acc = lvb[jj];
        #pragma unroll
        for (int k = 0; k < STATE; k++) acc += row[k] * lvW[k * M_OUT + jj];
        acc = fminf(fmaxf(acc, -20.f), 2.f);
        out[GRAPHS * M_OUT + g * M_OUT + jj] = expf(0.5f * acc);
    }
}

extern "C" void kernel_launch(void* const* d_in, const int* in_sizes, int n_in,
                              void* d_out, int out_size, void* d_ws, size_t ws_size,
                              hipStream_t stream) {
    const float* x     = (const float*)d_in[0];
    const int*   ei    = (const int*)d_in[1];   // [2, E]: row0 = src (gather), row1 = dst (scatter)
    const int*   batch = (const int*)d_in[2];
    const float* inW   = (const float*)d_in[3];
    const float* inb   = (const float*)d_in[4];
    const float* msgW  = (const float*)d_in[5]; // [4,64,64]
    const float* msgb  = (const float*)d_in[6]; // [4,64]
    const float* updW  = (const float*)d_in[7];
    const float* updb  = (const float*)d_in[8];
    const float* meanW = (const float*)d_in[9];
    const float* meanb = (const float*)d_in[10];
    const float* lvW   = (const float*)d_in[11];
    const float* lvb   = (const float*)d_in[12];
    float* out = (float*)d_out;

    const size_t NS = (size_t)NODES * STATE * sizeof(float); // 12.8 MB
    char* ws = (char*)d_ws;
    size_t off = 0;
    auto alloc = [&](size_t bytes) { void* p = ws + off; off += (bytes + 255) & ~(size_t)255; return p; };
    float* state   = (float*)alloc(NS);
    float* msgA    = (float*)alloc(NS);
    float* msgB    = (float*)alloc(NS);
    float* gs      = (float*)alloc((size_t)GRAPHS * STATE * sizeof(float));
    int*   deg2    = (int*)alloc((size_t)NODES * NB * sizeof(int));
    int*   rowptr  = (int*)alloc((size_t)(NODES + 1) * sizeof(int));
    int*   bptr    = (int*)alloc((size_t)(NODES * NB + 1) * sizeof(int));
    int*   cursor  = (int*)alloc((size_t)NODES * NB * sizeof(int));
    int*   csr     = (int*)alloc((size_t)EDGES * sizeof(int));

    hipMemsetAsync(deg2, 0, (size_t)NODES * NB * sizeof(int), stream);
    hipMemsetAsync(gs, 0, (size_t)GRAPHS * STATE * sizeof(float), stream);

    k_hist<<<(EDGES + 255) / 256, 256, 0, stream>>>(ei, deg2);
    k_scan<<<1, 1024, 0, stream>>>(deg2, rowptr);
    k_bptr<<<(NODES + 255) / 256, 256, 0, stream>>>(deg2, rowptr, bptr, cursor);
    k_fill<<<(EDGES + 255) / 256, 256, 0, stream>>>(ei, cursor, csr);

    k_in_msg<<<NTILES, 256, 0, stream>>>(x, inW, inb, msgW, msgb, state, msgA);

    float* mi = msgA; float* mo = msgB;
    for (int r = 0; r < ROUNDS - 1; r++) {
        k_agg_upd_msg<<<NTILES, 256, 0, stream>>>(
            updW + r * STATE * STATE, updb + r * STATE,
            msgW + (r + 1) * STATE * STATE, msgb + (r + 1) * STATE,
            bptr, csr, mi, state, mo);
        float* t = mi; mi = mo; mo = t;
    }
    k_agg_upd_pool<<<NTILES, 256, 0, stream>>>(
        updW + (ROUNDS - 1) * STATE * STATE, updb + (ROUNDS - 1) * STATE,
        bptr, csr, mi, state, batch, gs);

    k_final<<<GRAPHS, 64, 0, stream>>>(gs, meanW, meanb, lvW, lvb, out);
}

// Round 5
// 514.232 us; speedup vs baseline: 1.1212x; 1.1212x over previous
//
#include <hip/hip_runtime.h>
#include <math.h>

#define NODES  50000
#define EDGES  800000
#define GRAPHS 256
#define FEAT   128
#define STATE  64
#define M_OUT  32
#define ROUNDS 4
#define NTILES ((NODES + 15) / 16)

typedef unsigned short bfraw;

__device__ __forceinline__ float bf2f(bfraw u) {
    union { unsigned int i; float f; } v; v.i = ((unsigned int)u) << 16; return v.f;
}
__device__ __forceinline__ bfraw f2bf(float f) {
    union { float f; unsigned int i; } v; v.f = f;
    unsigned int r = v.i + 0x7FFF + ((v.i >> 16) & 1); // round-nearest-even
    return (bfraw)(r >> 16);
}

// ---------------------------------------------------------------------------
// 8-deep gather over bf16 message rows: sum of msg[csr[beg..end)] 4-feat
// slices at offset jg. Tail indices clamped to end-1, masked by 0-multiplier.
// Per thread per edge: one 8B ushort4 load (16 threads cover the 128B row).
// ---------------------------------------------------------------------------
__device__ __forceinline__ float4 gather_sum8(const int* __restrict__ csr,
                                              const bfraw* __restrict__ msg,
                                              int beg, int end, int jg)
{
    float4 acc = make_float4(0.f, 0.f, 0.f, 0.f);
    for (int i = beg; i < end; i += 8) {
        int last = end - 1;
        int i1 = i + 1 < last ? i + 1 : last;
        int i2 = i + 2 < last ? i + 2 : last;
        int i3 = i + 3 < last ? i + 3 : last;
        int i4 = i + 4 < last ? i + 4 : last;
        int i5 = i + 5 < last ? i + 5 : last;
        int i6 = i + 6 < last ? i + 6 : last;
        int i7 = i + 7 < last ? i + 7 : last;
        int s0 = csr[i],  s1 = csr[i1], s2 = csr[i2], s3 = csr[i3];
        int s4 = csr[i4], s5 = csr[i5], s6 = csr[i6], s7 = csr[i7];
        ushort4 v0 = *(const ushort4*)(msg + (long)s0 * STATE + jg);
        ushort4 v1 = *(const ushort4*)(msg + (long)s1 * STATE + jg);
        ushort4 v2 = *(const ushort4*)(msg + (long)s2 * STATE + jg);
        ushort4 v3 = *(const ushort4*)(msg + (long)s3 * STATE + jg);
        ushort4 v4 = *(const ushort4*)(msg + (long)s4 * STATE + jg);
        ushort4 v5 = *(const ushort4*)(msg + (long)s5 * STATE + jg);
        ushort4 v6 = *(const ushort4*)(msg + (long)s6 * STATE + jg);
        ushort4 v7 = *(const ushort4*)(msg + (long)s7 * STATE + jg);
        float m1 = (i + 1 < end) ? 1.f : 0.f;
        float m2 = (i + 2 < end) ? 1.f : 0.f;
        float m3 = (i + 3 < end) ? 1.f : 0.f;
        float m4 = (i + 4 < end) ? 1.f : 0.f;
        float m5 = (i + 5 < end) ? 1.f : 0.f;
        float m6 = (i + 6 < end) ? 1.f : 0.f;
        float m7 = (i + 7 < end) ? 1.f : 0.f;
        acc.x += bf2f(v0.x);      acc.y += bf2f(v0.y);      acc.z += bf2f(v0.z);      acc.w += bf2f(v0.w);
        acc.x += bf2f(v1.x) * m1; acc.y += bf2f(v1.y) * m1; acc.z += bf2f(v1.z) * m1; acc.w += bf2f(v1.w) * m1;
        acc.x += bf2f(v2.x) * m2; acc.y += bf2f(v2.y) * m2; acc.z += bf2f(v2.z) * m2; acc.w += bf2f(v2.w) * m2;
        acc.x += bf2f(v3.x) * m3; acc.y += bf2f(v3.y) * m3; acc.z += bf2f(v3.z) * m3; acc.w += bf2f(v3.w) * m3;
        acc.x += bf2f(v4.x) * m4; acc.y += bf2f(v4.y) * m4; acc.z += bf2f(v4.z) * m4; acc.w += bf2f(v4.w) * m4;
        acc.x += bf2f(v5.x) * m5; acc.y += bf2f(v5.y) * m5; acc.z += bf2f(v5.z) * m5; acc.w += bf2f(v5.w) * m5;
        acc.x += bf2f(v6.x) * m6; acc.y += bf2f(v6.y) * m6; acc.z += bf2f(v6.z) * m6; acc.w += bf2f(v6.w) * m6;
        acc.x += bf2f(v7.x) * m7; acc.y += bf2f(v7.y) * m7; acc.z += bf2f(v7.z) * m7; acc.w += bf2f(v7.w) * m7;
    }
    return acc;
}

__device__ __forceinline__ void store_bf4(bfraw* p, float a, float b, float c, float d) {
    ushort4 u; u.x = f2bf(a); u.y = f2bf(b); u.z = f2bf(c); u.w = f2bf(d);
    *(ushort4*)p = u;
}

// ---------------------------------------------------------------------------
// Fused: state = relu(x @ inW + inb); message(bf16) = relu(state @ msgW + msgb)
// ---------------------------------------------------------------------------
__global__ __launch_bounds__(256) void k_in_msg(
    const float* __restrict__ x, const float* __restrict__ inW, const float* __restrict__ inb,
    const float* __restrict__ msgW, const float* __restrict__ msgb,
    float* __restrict__ state, bfraw* __restrict__ message)
{
    __shared__ float sInW[FEAT * STATE];    // 32 KB
    __shared__ float sMsgW[STATE * STATE];  // 16 KB
    __shared__ float sInb[STATE], sMsgb[STATE];
    __shared__ float sx[16 * 132];
    __shared__ float ss[16 * 68];

    for (int i = threadIdx.x; i < (FEAT * STATE) / 4; i += 256)
        *(float4*)(sInW + i * 4) = *(const float4*)(inW + i * 4);
    for (int i = threadIdx.x; i < (STATE * STATE) / 4; i += 256)
        *(float4*)(sMsgW + i * 4) = *(const float4*)(msgW + i * 4);
    if (threadIdx.x < STATE) {
        sInb[threadIdx.x]  = inb[threadIdx.x];
        sMsgb[threadIdx.x] = msgb[threadIdx.x];
    }

    const int ns = threadIdx.x >> 4;
    const int jg = (threadIdx.x & 15) << 2;

    for (int base = blockIdx.x * 16; base < NODES; base += gridDim.x * 16) {
        __syncthreads();
        for (int i = threadIdx.x; i < 512; i += 256) {
            int row = i >> 5, q = (i & 31) << 2;
            int n = base + row;
            float4 v = make_float4(0.f, 0.f, 0.f, 0.f);
            if (n < NODES) v = *(const float4*)(x + (long)n * FEAT + q);
            *(float4*)(sx + row * 132 + q) = v;
        }
        __syncthreads();

        const int n = base + ns;
        float a0 = sInb[jg], a1 = sInb[jg + 1], a2 = sInb[jg + 2], a3 = sInb[jg + 3];
        const float* xr = sx + ns * 132;
        #pragma unroll 8
        for (int k = 0; k < FEAT; k++) {
            float xv = xr[k];
            float4 w = *(const float4*)(sInW + k * STATE + jg);
            a0 += xv * w.x; a1 += xv * w.y; a2 += xv * w.z; a3 += xv * w.w;
        }
        a0 = fmaxf(a0, 0.f); a1 = fmaxf(a1, 0.f); a2 = fmaxf(a2, 0.f); a3 = fmaxf(a3, 0.f);
        if (n < NODES) *(float4*)(state + (long)n * STATE + jg) = make_float4(a0, a1, a2, a3);
        *(float4*)(ss + ns * 68 + jg) = make_float4(a0, a1, a2, a3);
        __syncthreads();

        float m0 = sMsgb[jg], m1 = sMsgb[jg + 1], m2 = sMsgb[jg + 2], m3 = sMsgb[jg + 3];
        const float* sr = ss + ns * 68;
        #pragma unroll 8
        for (int k = 0; k < STATE; k++) {
            float sv = sr[k];
            float4 w = *(const float4*)(sMsgW + k * STATE + jg);
            m0 += sv * w.x; m1 += sv * w.y; m2 += sv * w.z; m3 += sv * w.w;
        }
        m0 = fmaxf(m0, 0.f); m1 = fmaxf(m1, 0.f); m2 = fmaxf(m2, 0.f); m3 = fmaxf(m3, 0.f);
        if (n < NODES) store_bf4(message + (long)n * STATE + jg, m0, m1, m2, m3);
    }
}

// ---------------------------------------------------------------------------
// CSR build (flat, dst-major)
// ---------------------------------------------------------------------------
__global__ __launch_bounds__(256) void k_hist(const int* __restrict__ ei, int* __restrict__ deg)
{
    int e = blockIdx.x * 256 + threadIdx.x;
    if (e < EDGES) atomicAdd(&deg[ei[EDGES + e]], 1);
}

__global__ __launch_bounds__(1024) void k_scan(const int* __restrict__ deg,
                                               int* __restrict__ rowptr,
                                               int* __restrict__ cursor)
{
    __shared__ int wsum[16];
    __shared__ int carry;
    const int tid = threadIdx.x;
    const int lane = tid & 63, wid = tid >> 6;
    if (tid == 0) carry = 0;
    __syncthreads();
    for (int base = 0; base < NODES; base += 1024) {
        int v = (base + tid < NODES) ? deg[base + tid] : 0;
        int incl = v;
        #pragma unroll
        for (int off = 1; off < 64; off <<= 1) {
            int t = __shfl_up(incl, off, 64);
            if (lane >= off) incl += t;
        }
        if (lane == 63) wsum[wid] = incl;
        __syncthreads();
        if (tid < 16) {
            int t = wsum[tid];
            #pragma unroll
            for (int off = 1; off < 16; off <<= 1) {
                int u = __shfl_up(t, off, 64);
                if (tid >= off) t += u;
            }
            wsum[tid] = t;
        }
        __syncthreads();
        int wbase = (wid == 0) ? 0 : wsum[wid - 1];
        int excl = carry + wbase + incl - v;
        if (base + tid < NODES) { rowptr[base + tid] = excl; cursor[base + tid] = excl; }
        int tot = wsum[15];
        __syncthreads();
        if (tid == 0) carry += tot;
        __syncthreads();
    }
    if (tid == 0) rowptr[NODES] = carry;
}

__global__ __launch_bounds__(256) void k_fill(const int* __restrict__ ei,
                                              int* __restrict__ cursor,
                                              int* __restrict__ csr)
{
    int e = blockIdx.x * 256 + threadIdx.x;
    if (e < EDGES) {
        int src = ei[e];
        int dst = ei[EDGES + e];
        int slot = atomicAdd(&cursor[dst], 1);
        csr[slot] = src;
    }
}

// ---------------------------------------------------------------------------
// Pull aggregation (bf16 gather) fused with update + next message.
// ---------------------------------------------------------------------------
__global__ __launch_bounds__(256) void k_agg_upd_msg(
    const float* __restrict__ updW, const float* __restrict__ updb,
    const float* __restrict__ msgW, const float* __restrict__ msgb,
    const int* __restrict__ rowptr, const int* __restrict__ csr,
    const bfraw* __restrict__ msg_in,
    float* __restrict__ state, bfraw* __restrict__ msg_out)
{
    __shared__ float sUpdW[STATE * STATE], sMsgW[STATE * STATE];
    __shared__ float sUpdb[STATE], sMsgb[STATE];
    __shared__ float sa[16 * 68], ss[16 * 68];

    for (int i = threadIdx.x; i < (STATE * STATE) / 4; i += 256) {
        *(float4*)(sUpdW + i * 4) = *(const float4*)(updW + i * 4);
        *(float4*)(sMsgW + i * 4) = *(const float4*)(msgW + i * 4);
    }
    if (threadIdx.x < STATE) {
        sUpdb[threadIdx.x] = updb[threadIdx.x];
        sMsgb[threadIdx.x] = msgb[threadIdx.x];
    }

    const int ns = threadIdx.x >> 4;
    const int jg = (threadIdx.x & 15) << 2;

    for (int base = blockIdx.x * 16; base < NODES; base += gridDim.x * 16) {
        const int n = base + ns;
        float4 acc = make_float4(0.f, 0.f, 0.f, 0.f);
        if (n < NODES) {
            int beg = rowptr[n], end = rowptr[n + 1];
            acc = gather_sum8(csr, msg_in, beg, end, jg);
        }
        __syncthreads();
        *(float4*)(sa + ns * 68 + jg) = acc;
        __syncthreads();

        float a0 = sUpdb[jg], a1 = sUpdb[jg + 1], a2 = sUpdb[jg + 2], a3 = sUpdb[jg + 3];
        const float* ar = sa + ns * 68;
        #pragma unroll 8
        for (int k = 0; k < STATE; k++) {
            float av = ar[k];
            float4 w = *(const float4*)(sUpdW + k * STATE + jg);
            a0 += av * w.x; a1 += av * w.y; a2 += av * w.z; a3 += av * w.w;
        }
        a0 = fmaxf(a0, 0.f); a1 = fmaxf(a1, 0.f); a2 = fmaxf(a2, 0.f); a3 = fmaxf(a3, 0.f);
        float4 st = make_float4(0.f, 0.f, 0.f, 0.f);
        if (n < NODES) st = *(const float4*)(state + (long)n * STATE + jg);
        float s0 = st.x + a0, s1 = st.y + a1, s2 = st.z + a2, s3 = st.w + a3;
        if (n < NODES) *(float4*)(state + (long)n * STATE + jg) = make_float4(s0, s1, s2, s3);
        *(float4*)(ss + ns * 68 + jg) = make_float4(s0, s1, s2, s3);
        __syncthreads();

        float m0 = sMsgb[jg], m1 = sMsgb[jg + 1], m2 = sMsgb[jg + 2], m3 = sMsgb[jg + 3];
        const float* sr = ss + ns * 68;
        #pragma unroll 8
        for (int k = 0; k < STATE; k++) {
            float sv = sr[k];
            float4 w = *(const float4*)(sMsgW + k * STATE + jg);
            m0 += sv * w.x; m1 += sv * w.y; m2 += sv * w.z; m3 += sv * w.w;
        }
        m0 = fmaxf(m0, 0.f); m1 = fmaxf(m1, 0.f); m2 = fmaxf(m2, 0.f); m3 = fmaxf(m3, 0.f);
        if (n < NODES) store_bf4(msg_out + (long)n * STATE + jg, m0, m1, m2, m3);
    }
}

// ---------------------------------------------------------------------------
// Last round: aggregation + update fused with graph pooling.
// ---------------------------------------------------------------------------
__global__ __launch_bounds__(256) void k_agg_upd_pool(
    const float* __restrict__ updW, const float* __restrict__ updb,
    const int* __restrict__ rowptr, const int* __restrict__ csr,
    const bfraw* __restrict__ msg_in,
    const float* __restrict__ state, const int* __restrict__ batch,
    float* __restrict__ gs)
{
    __shared__ float sUpdW[STATE * STATE];
    __shared__ float sUpdb[STATE];
    __shared__ float sa[16 * 68];

    for (int i = threadIdx.x; i < (STATE * STATE) / 4; i += 256)
        *(float4*)(sUpdW + i * 4) = *(const float4*)(updW + i * 4);
    if (threadIdx.x < STATE) sUpdb[threadIdx.x] = updb[threadIdx.x];

    const int ns = threadIdx.x >> 4;
    const int jg = (threadIdx.x & 15) << 2;

    for (int base = blockIdx.x * 16; base < NODES; base += gridDim.x * 16) {
        const int n = base + ns;
        float4 acc = make_float4(0.f, 0.f, 0.f, 0.f);
        if (n < NODES) {
            int beg = rowptr[n], end = rowptr[n + 1];
            acc = gather_sum8(csr, msg_in, beg, end, jg);
        }
        __syncthreads();
        *(float4*)(sa + ns * 68 + jg) = acc;
        __syncthreads();

        float a0 = sUpdb[jg], a1 = sUpdb[jg + 1], a2 = sUpdb[jg + 2], a3 = sUpdb[jg + 3];
        const float* ar = sa + ns * 68;
        #pragma unroll 8
        for (int k = 0; k < STATE; k++) {
            float av = ar[k];
            float4 w = *(const float4*)(sUpdW + k * STATE + jg);
            a0 += av * w.x; a1 += av * w.y; a2 += av * w.z; a3 += av * w.w;
        }
        a0 = fmaxf(a0, 0.f); a1 = fmaxf(a1, 0.f); a2 = fmaxf(a2, 0.f); a3 = fmaxf(a3, 0.f);
        if (n < NODES) {
            float4 st = *(const float4*)(state + (long)n * STATE + jg);
            int g = batch[n];
            float* p = gs + (long)g * STATE + jg;
            atomicAdd(p + 0, st.x + a0);
            atomicAdd(p + 1, st.y + a1);
            atomicAdd(p + 2, st.z + a2);
            atomicAdd(p + 3, st.w + a3);
        }
        __syncthreads();
    }
}

// ---------------------------------------------------------------------------
// mean = gs@meanW+b ; std = exp(0.5*clip(gs@lvW+b, -20, 2)) -> out[2,256,32]
// ---------------------------------------------------------------------------
__global__ __launch_bounds__(64) void k_final(
    const float* __restrict__ gs,
    const float* __restrict__ meanW, const float* __restrict__ meanb,
    const float* __restrict__ lvW, const float* __restrict__ lvb,
    float* __restrict__ out)
{
    __shared__ float row[STATE];
    const int g = blockIdx.x;
    const int j = threadIdx.x;
    row[j] = gs[g * STATE + j];
    __syncthreads();
    if (j < M_OUT) {
        float acc = meanb[j];
        #pragma unroll
        for (int k = 0; k < STATE; k++) acc += row[k] * meanW[k * M_OUT + j];
        out[g * M_OUT + j] = acc;
    } else {
        int jj = j - M_OUT;
        float acc = lvb[jj];
        #pragma unroll
        for (int k = 0; k < STATE; k++) acc += row[k] * lvW[k * M_OUT + jj];
        acc = fminf(fmaxf(acc, -20.f), 2.f);
        out[GRAPHS * M_OUT + g * M_OUT + jj] = expf(0.5f * acc);
    }
}

extern "C" void kernel_launch(void* const* d_in, const int* in_sizes, int n_in,
                              void* d_out, int out_size, void* d_ws, size_t ws_size,
                              hipStream_t stream) {
    const float* x     = (const float*)d_in[0];
    const int*   ei    = (const int*)d_in[1];   // [2, E]: row0 = src (gather), row1 = dst (scatter)
    const int*   batch = (const int*)d_in[2];
    const float* inW   = (const float*)d_in[3];
    const float* inb   = (const float*)d_in[4];
    const float* msgW  = (const float*)d_in[5]; // [4,64,64]
    const float* msgb  = (const float*)d_in[6]; // [4,64]
    const float* updW  = (const float*)d_in[7];
    const float* updb  = (const float*)d_in[8];
    const float* meanW = (const float*)d_in[9];
    const float* meanb = (const float*)d_in[10];
    const float* lvW   = (const float*)d_in[11];
    const float* lvb   = (const float*)d_in[12];
    float* out = (float*)d_out;

    const size_t NS  = (size_t)NODES * STATE * sizeof(float); // 12.8 MB (state)
    const size_t NSH = (size_t)NODES * STATE * sizeof(bfraw); //  6.4 MB (bf16 messages)
    char* ws = (char*)d_ws;
    size_t off = 0;
    auto alloc = [&](size_t bytes) { void* p = ws + off; off += (bytes + 255) & ~(size_t)255; return p; };
    float* state   = (float*)alloc(NS);
    bfraw* msgA    = (bfraw*)alloc(NSH);
    bfraw* msgB    = (bfraw*)alloc(NSH);
    float* gs      = (float*)alloc((size_t)GRAPHS * STATE * sizeof(float));
    int*   deg     = (int*)alloc((size_t)NODES * sizeof(int));
    int*   rowptr  = (int*)alloc((size_t)(NODES + 1) * sizeof(int));
    int*   cursor  = (int*)alloc((size_t)NODES * sizeof(int));
    int*   csr     = (int*)alloc((size_t)EDGES * sizeof(int));

    hipMemsetAsync(deg, 0, (size_t)NODES * sizeof(int), stream);
    hipMemsetAsync(gs, 0, (size_t)GRAPHS * STATE * sizeof(float), stream);

    k_hist<<<(EDGES + 255) / 256, 256, 0, stream>>>(ei, deg);
    k_scan<<<1, 1024, 0, stream>>>(deg, rowptr, cursor);
    k_fill<<<(EDGES + 255) / 256, 256, 0, stream>>>(ei, cursor, csr);

    k_in_msg<<<NTILES, 256, 0, stream>>>(x, inW, inb, msgW, msgb, state, msgA);

    bfraw* mi = msgA; bfraw* mo = msgB;
    for (int r = 0; r < ROUNDS - 1; r++) {
        k_agg_upd_msg<<<NTILES, 256, 0, stream>>>(
            updW + r * STATE * STATE, updb + r * STATE,
            msgW + (r + 1) * STATE * STATE, msgb + (r + 1) * STATE,
            rowptr, csr, mi, state, mo);
        bfraw* t = mi; mi = mo; mo = t;
    }
    k_agg_upd_pool<<<NTILES, 256, 0, stream>>>(
        updW + (ROUNDS - 1) * STATE * STATE, updb + (ROUNDS - 1) * STATE,
        rowptr, csr, mi, state, batch, gs);

    k_final<<<GRAPHS, 64, 0, stream>>>(gs, meanW, meanb, lvW, lvb, out);
}